// Round 2
// baseline (1979.044 us; speedup 1.0000x reference)
//
#include <hip/hip_runtime.h>
#include <cstddef>

// Problem constants (match reference)
#define N_NODES 100000
#define N_EDGES 1600000
#define E_TOT   (N_EDGES + N_NODES)   // edges + self loops = 1,700,000
#define IN_DIM  64
#define HIDDEN  128
#define Z_DIM   64

// ---------------- CSR build ----------------

__global__ __launch_bounds__(256) void init_cnt_k(int* cnt, int n) {
    int i = blockIdx.x * 256 + threadIdx.x;
    if (i < n) cnt[i] = 1;   // self loop
}

__global__ __launch_bounds__(256) void count_k(const int* __restrict__ dst, int* cnt, int e) {
    int i = blockIdx.x * 256 + threadIdx.x;
    if (i < e) atomicAdd(&cnt[dst[i]], 1);
}

__global__ __launch_bounds__(256) void dinv_k(const int* __restrict__ cnt, float* __restrict__ dinv, int n) {
    int i = blockIdx.x * 256 + threadIdx.x;
    if (i < n) dinv[i] = rsqrtf((float)cnt[i]);   // cnt >= 1 always
}

__global__ __launch_bounds__(256) void scan_block_k(const int* __restrict__ cnt, int* __restrict__ rowptr,
                                                    int* __restrict__ bsum, int n) {
    __shared__ int s[256];
    int tid = threadIdx.x;
    int i = blockIdx.x * 256 + tid;
    int v = (i < n) ? cnt[i] : 0;
    s[tid] = v;
    __syncthreads();
#pragma unroll
    for (int off = 1; off < 256; off <<= 1) {
        int t = (tid >= off) ? s[tid - off] : 0;
        __syncthreads();
        s[tid] += t;
        __syncthreads();
    }
    if (i < n) rowptr[i] = s[tid] - v;        // exclusive within block
    if (tid == 255) bsum[blockIdx.x] = s[255];
}

__global__ __launch_bounds__(512) void scan_bsum_k(int* bsum, int nb) {
    __shared__ int s[512];
    int tid = threadIdx.x;
    int v = (tid < nb) ? bsum[tid] : 0;
    s[tid] = v;
    __syncthreads();
#pragma unroll
    for (int off = 1; off < 512; off <<= 1) {
        int t = (tid >= off) ? s[tid - off] : 0;
        __syncthreads();
        s[tid] += t;
        __syncthreads();
    }
    if (tid < nb) bsum[tid] = s[tid] - v;     // exclusive
}

__global__ __launch_bounds__(256) void scan_add_k(int* __restrict__ rowptr, const int* __restrict__ bsum,
                                                  int* __restrict__ cursor, int n, int etot) {
    int i = blockIdx.x * 256 + threadIdx.x;
    if (i < n) {
        int val = rowptr[i] + bsum[blockIdx.x];
        rowptr[i] = val;
        cursor[i] = val;
    }
    if (i == 0) rowptr[n] = etot;
}

__global__ __launch_bounds__(256) void fill_k(const int* __restrict__ src, const int* __restrict__ dst,
                                              const float* __restrict__ dinv, int* cursor,
                                              int* __restrict__ col, float* __restrict__ nrm,
                                              int e, int n) {
    int i = blockIdx.x * 256 + threadIdx.x;
    if (i < e) {
        int s = src[i], d = dst[i];
        int p = atomicAdd(&cursor[d], 1);
        col[p] = s;
        nrm[p] = dinv[s] * dinv[d];
    } else if (i < e + n) {
        int v = i - e;
        int p = atomicAdd(&cursor[v], 1);
        col[p] = v;
        float dv = dinv[v];
        nrm[p] = dv * dv;
    }
}

// ---------------- Aggregation (gather): one wave per node ----------------

template <int DIM>
__global__ __launch_bounds__(256) void agg_k(const float* __restrict__ H, const int* __restrict__ rowptr,
                                             const int* __restrict__ col, const float* __restrict__ nrm,
                                             float* __restrict__ out, int n) {
    int node = (int)((blockIdx.x * 256 + threadIdx.x) >> 6);
    if (node >= n) return;
    int lane = threadIdx.x & 63;
    int beg = rowptr[node], end = rowptr[node + 1];
    if constexpr (DIM == 64) {
        float acc = 0.f;
        int j = beg;
        for (; j + 4 <= end; j += 4) {
            int   s0 = col[j + 0], s1 = col[j + 1], s2 = col[j + 2], s3 = col[j + 3];
            float w0 = nrm[j + 0], w1 = nrm[j + 1], w2 = nrm[j + 2], w3 = nrm[j + 3];
            float v0 = H[(size_t)s0 * 64 + lane];
            float v1 = H[(size_t)s1 * 64 + lane];
            float v2 = H[(size_t)s2 * 64 + lane];
            float v3 = H[(size_t)s3 * 64 + lane];
            acc += w0 * v0; acc += w1 * v1; acc += w2 * v2; acc += w3 * v3;
        }
        for (; j < end; j++) acc += nrm[j] * H[(size_t)col[j] * 64 + lane];
        out[(size_t)node * 64 + lane] = acc;
    } else {
        const float2* H2 = (const float2*)H;
        float2 acc; acc.x = 0.f; acc.y = 0.f;
        int j = beg;
        for (; j + 4 <= end; j += 4) {
            int   s0 = col[j + 0], s1 = col[j + 1], s2 = col[j + 2], s3 = col[j + 3];
            float w0 = nrm[j + 0], w1 = nrm[j + 1], w2 = nrm[j + 2], w3 = nrm[j + 3];
            float2 v0 = H2[(size_t)s0 * 64 + lane];
            float2 v1 = H2[(size_t)s1 * 64 + lane];
            float2 v2 = H2[(size_t)s2 * 64 + lane];
            float2 v3 = H2[(size_t)s3 * 64 + lane];
            acc.x += w0 * v0.x; acc.y += w0 * v0.y;
            acc.x += w1 * v1.x; acc.y += w1 * v1.y;
            acc.x += w2 * v2.x; acc.y += w2 * v2.y;
            acc.x += w3 * v3.x; acc.y += w3 * v3.y;
        }
        for (; j < end; j++) {
            float w = nrm[j];
            float2 v = H2[(size_t)col[j] * 64 + lane];
            acc.x += w * v.x; acc.y += w * v.y;
        }
        ((float2*)out)[(size_t)node * 64 + lane] = acc;
    }
}

// ---------------- Dense layer, F=128 outputs, conflict-free LDS ----------------
// Block = 256 threads, 64 nodes/block (2 nodes per thread), K chunked by 64.
// Thread t: node pair mp=(t>>3)*2, feature group fg=t&7 owning feats fg*4+32*j (j=0..3).
// Per ds_read_b128 of Ws: 8 distinct addrs (fg=0..7) -> banks 4fg..4fg+3 = all 32 banks,
// zero conflicts (vs 4-way in R1 contiguous mapping -> SQ_LDS_BANK_CONFLICT 2.56e7).
// DUAL: output cols 0..63 = Wa/ba -> Ca, 64..127 = Wb/bb -> Cb (fused mu/logvar heads).

template <int K, bool RELU, bool DUAL>
__global__ __launch_bounds__(256) void gemm128_k(const float* __restrict__ A,
                                                 const float* __restrict__ Wa, const float* __restrict__ Wb,
                                                 const float* __restrict__ ba, const float* __restrict__ bb,
                                                 float* __restrict__ Ca, float* __restrict__ Cb, int n) {
    constexpr int F  = 128;
    constexpr int NT = 64;
    constexpr int KC = 64;
    constexpr int AP = 68;           // A-tile pad: 2-way residue only (free)
    __shared__ __align__(16) float Ws[KC * F];
    __shared__ __align__(16) float As[NT * AP];

    int t  = threadIdx.x;
    int m0 = blockIdx.x * NT;
    int mp = (t >> 3) * 2;           // local node pair base
    int fg = t & 7;

    float4 acc0[4], acc1[4];
#pragma unroll
    for (int j = 0; j < 4; j++) {
        acc0[j].x = 0.f; acc0[j].y = 0.f; acc0[j].z = 0.f; acc0[j].w = 0.f;
        acc1[j].x = 0.f; acc1[j].y = 0.f; acc1[j].z = 0.f; acc1[j].w = 0.f;
    }

    for (int kc = 0; kc < K; kc += KC) {
        // stage Ws (KC x 128), float4-vectorized: 2048 float4 / 256 thr = 8 each
#pragma unroll
        for (int e = t; e < KC * F / 4; e += 256) {
            float4 w;
            if (!DUAL) {
                w = ((const float4*)Wa)[(size_t)kc * (F / 4) + e];
            } else {
                int r = e >> 5;              // k row within chunk
                int c = (e & 31) * 4;        // float col 0..127
                const float* s = (c < 64) ? &Wa[(size_t)(kc + r) * 64 + c]
                                          : &Wb[(size_t)(kc + r) * 64 + (c - 64)];
                w = *(const float4*)s;
            }
            ((float4*)Ws)[e] = w;
        }
        // stage As (NT x KC, pad AP): 1024 float4 / 256 thr = 4 each
#pragma unroll
        for (int e = t; e < NT * KC / 4; e += 256) {
            int r = e >> 4;
            int c = (e & 15) * 4;
            float4 v;
            if (m0 + r < n) v = *(const float4*)&A[(size_t)(m0 + r) * K + kc + c];
            else { v.x = 0.f; v.y = 0.f; v.z = 0.f; v.w = 0.f; }
            *(float4*)&As[r * AP + c] = v;
        }
        __syncthreads();

#pragma unroll
        for (int k4 = 0; k4 < KC; k4 += 4) {
            float4 a0 = *(const float4*)&As[mp * AP + k4];
            float4 a1 = *(const float4*)&As[(mp + 1) * AP + k4];
            const float ax[4] = {a0.x, a0.y, a0.z, a0.w};
            const float ay[4] = {a1.x, a1.y, a1.z, a1.w};
#pragma unroll
            for (int kk = 0; kk < 4; kk++) {
#pragma unroll
                for (int j = 0; j < 4; j++) {
                    float4 w = *(const float4*)&Ws[(k4 + kk) * F + fg * 4 + 32 * j];
                    acc0[j].x += ax[kk] * w.x; acc0[j].y += ax[kk] * w.y;
                    acc0[j].z += ax[kk] * w.z; acc0[j].w += ax[kk] * w.w;
                    acc1[j].x += ay[kk] * w.x; acc1[j].y += ay[kk] * w.y;
                    acc1[j].z += ay[kk] * w.z; acc1[j].w += ay[kk] * w.w;
                }
            }
        }
        __syncthreads();
    }

    // epilogue: bias + optional relu, split store when DUAL
#pragma unroll
    for (int nn = 0; nn < 2; nn++) {
        int node = m0 + mp + nn;
        if (node >= n) break;
#pragma unroll
        for (int j = 0; j < 4; j++) {
            int f = fg * 4 + 32 * j;
            float4 v = nn ? acc1[j] : acc0[j];
            const float* bp;
            float* cp;
            int fo;
            if (!DUAL) {
                bp = ba; cp = Ca + (size_t)node * F; fo = f;
            } else if (f < 64) {
                bp = ba; cp = Ca + (size_t)node * 64; fo = f;
            } else {
                bp = bb; cp = Cb + (size_t)node * 64; fo = f - 64;
            }
            v.x += bp[fo + 0]; v.y += bp[fo + 1]; v.z += bp[fo + 2]; v.w += bp[fo + 3];
            if (RELU) {
                v.x = fmaxf(v.x, 0.f); v.y = fmaxf(v.y, 0.f);
                v.z = fmaxf(v.z, 0.f); v.w = fmaxf(v.w, 0.f);
            }
            *(float4*)&cp[fo] = v;
        }
    }
}

// ---------------- launch ----------------

extern "C" void kernel_launch(void* const* d_in, const int* in_sizes, int n_in,
                              void* d_out, int out_size, void* d_ws, size_t ws_size,
                              hipStream_t stream) {
    const int N = N_NODES, E = N_EDGES, ETOT = E_TOT;

    const float* x    = (const float*)d_in[0];
    const int*   ei   = (const int*)d_in[1];
    const int*   srcA = ei;
    const int*   dstA = ei + E;
    const float* W1   = (const float*)d_in[2];
    const float* b1   = (const float*)d_in[3];
    const float* W2   = (const float*)d_in[4];
    const float* b2   = (const float*)d_in[5];
    const float* Wmu  = (const float*)d_in[6];
    const float* bmu  = (const float*)d_in[7];
    const float* Wlv  = (const float*)d_in[8];
    const float* blv  = (const float*)d_in[9];
    float* out = (float*)d_out;

    // workspace carve-out (~117 MB)
    char* ws = (char*)d_ws;
    size_t o = 0;
    auto alloc = [&](size_t bytes) -> void* {
        o = (o + 255) & ~(size_t)255;
        void* p = ws + o;
        o += bytes;
        return p;
    };
    int*   cnt    = (int*)alloc((size_t)N * 4);          // deg counts, later cursor
    int*   rowptr = (int*)alloc((size_t)(N + 1) * 4);
    float* dinv   = (float*)alloc((size_t)N * 4);
    int*   bsum   = (int*)alloc(512 * 4);
    int*   col    = (int*)alloc((size_t)ETOT * 4);
    float* nrm    = (float*)alloc((size_t)ETOT * 4);
    float* agg    = (float*)alloc((size_t)N * HIDDEN * 4);
    float* h      = (float*)alloc((size_t)N * HIDDEN * 4);
    (void)ws_size;

    const int gN = (N + 255) / 256;          // 391
    const int gE = (E + 255) / 256;          // 6250
    const int gT = (ETOT + 255) / 256;       // 6641
    const int gAgg = (N + 3) / 4;            // 25000 (4 nodes/block)
    const int gGemm = (N + 63) / 64;         // 1563

    // CSR build
    init_cnt_k<<<gN, 256, 0, stream>>>(cnt, N);
    count_k<<<gE, 256, 0, stream>>>(dstA, cnt, E);
    dinv_k<<<gN, 256, 0, stream>>>(cnt, dinv, N);
    scan_block_k<<<gN, 256, 0, stream>>>(cnt, rowptr, bsum, N);
    scan_bsum_k<<<1, 512, 0, stream>>>(bsum, gN);
    scan_add_k<<<gN, 256, 0, stream>>>(rowptr, bsum, cnt /*cursor*/, N, ETOT);
    fill_k<<<gT, 256, 0, stream>>>(srcA, dstA, dinv, cnt, col, nrm, E, N);

    // layer 1: h = relu(Agg(x) @ W1 + b1)      (aggregate in 64-dim!)
    agg_k<64><<<gAgg, 256, 0, stream>>>(x, rowptr, col, nrm, agg, N);
    gemm128_k<64, true, false><<<gGemm, 256, 0, stream>>>(agg, W1, nullptr, b1, nullptr, h, nullptr, N);

    // layer 2: h = relu(Agg(h) @ W2 + b2)
    agg_k<128><<<gAgg, 256, 0, stream>>>(h, rowptr, col, nrm, agg, N);
    gemm128_k<128, true, false><<<gGemm, 256, 0, stream>>>(agg, W2, nullptr, b2, nullptr, h, nullptr, N);

    // heads: aggregate once, ONE fused GEMM (cols 0..63 = mu, 64..127 = logvar)
    agg_k<128><<<gAgg, 256, 0, stream>>>(h, rowptr, col, nrm, agg, N);
    gemm128_k<128, false, true><<<gGemm, 256, 0, stream>>>(agg, Wmu, Wlv, bmu, blv,
                                                           out, out + (size_t)N * Z_DIM, N);
}

// Round 3
// 699.007 us; speedup vs baseline: 2.8312x; 2.8312x over previous
//
#include <hip/hip_runtime.h>
#include <cstddef>

// Problem constants (match reference)
#define N_NODES 100000
#define N_EDGES 1600000
#define E_TOT   (N_EDGES + N_NODES)   // edges + self loops = 1,700,000
#define IN_DIM  64
#define HIDDEN  128
#define Z_DIM   64

// ---------------- CSR build ----------------

__global__ __launch_bounds__(256) void init_cnt_k(int* cnt, int n) {
    int i = blockIdx.x * 256 + threadIdx.x;
    if (i < n) cnt[i] = 1;   // self loop
}

__global__ __launch_bounds__(256) void count_k(const int* __restrict__ dst, int* cnt, int e) {
    int i = blockIdx.x * 256 + threadIdx.x;
    if (i < e) atomicAdd(&cnt[dst[i]], 1);
}

__global__ __launch_bounds__(256) void dinv_k(const int* __restrict__ cnt, float* __restrict__ dinv, int n) {
    int i = blockIdx.x * 256 + threadIdx.x;
    if (i < n) dinv[i] = rsqrtf((float)cnt[i]);   // cnt >= 1 always
}

__global__ __launch_bounds__(256) void scan_block_k(const int* __restrict__ cnt, int* __restrict__ rowptr,
                                                    int* __restrict__ bsum, int n) {
    __shared__ int s[256];
    int tid = threadIdx.x;
    int i = blockIdx.x * 256 + tid;
    int v = (i < n) ? cnt[i] : 0;
    s[tid] = v;
    __syncthreads();
#pragma unroll
    for (int off = 1; off < 256; off <<= 1) {
        int t = (tid >= off) ? s[tid - off] : 0;
        __syncthreads();
        s[tid] += t;
        __syncthreads();
    }
    if (i < n) rowptr[i] = s[tid] - v;        // exclusive within block
    if (tid == 255) bsum[blockIdx.x] = s[255];
}

__global__ __launch_bounds__(512) void scan_bsum_k(int* bsum, int nb) {
    __shared__ int s[512];
    int tid = threadIdx.x;
    int v = (tid < nb) ? bsum[tid] : 0;
    s[tid] = v;
    __syncthreads();
#pragma unroll
    for (int off = 1; off < 512; off <<= 1) {
        int t = (tid >= off) ? s[tid - off] : 0;
        __syncthreads();
        s[tid] += t;
        __syncthreads();
    }
    if (tid < nb) bsum[tid] = s[tid] - v;     // exclusive
}

__global__ __launch_bounds__(256) void scan_add_k(int* __restrict__ rowptr, const int* __restrict__ bsum,
                                                  int* __restrict__ cursor, int n, int etot) {
    int i = blockIdx.x * 256 + threadIdx.x;
    if (i < n) {
        int val = rowptr[i] + bsum[blockIdx.x];
        rowptr[i] = val;
        cursor[i] = val;
    }
    if (i == 0) rowptr[n] = etot;
}

__global__ __launch_bounds__(256) void fill_k(const int* __restrict__ src, const int* __restrict__ dst,
                                              const float* __restrict__ dinv, int* cursor,
                                              int* __restrict__ col, float* __restrict__ nrm,
                                              int e, int n) {
    int i = blockIdx.x * 256 + threadIdx.x;
    if (i < e) {
        int s = src[i], d = dst[i];
        int p = atomicAdd(&cursor[d], 1);
        col[p] = s;
        nrm[p] = dinv[s] * dinv[d];
    } else if (i < e + n) {
        int v = i - e;
        int p = atomicAdd(&cursor[v], 1);
        col[p] = v;
        float dv = dinv[v];
        nrm[p] = dv * dv;
    }
}

// ---------------- Aggregation (gather): one wave per node ----------------

template <int DIM>
__global__ __launch_bounds__(256) void agg_k(const float* __restrict__ H, const int* __restrict__ rowptr,
                                             const int* __restrict__ col, const float* __restrict__ nrm,
                                             float* __restrict__ out, int n) {
    int node = (int)((blockIdx.x * 256 + threadIdx.x) >> 6);
    if (node >= n) return;
    int lane = threadIdx.x & 63;
    int beg = rowptr[node], end = rowptr[node + 1];
    if constexpr (DIM == 64) {
        float acc = 0.f;
        int j = beg;
        for (; j + 4 <= end; j += 4) {
            int   s0 = col[j + 0], s1 = col[j + 1], s2 = col[j + 2], s3 = col[j + 3];
            float w0 = nrm[j + 0], w1 = nrm[j + 1], w2 = nrm[j + 2], w3 = nrm[j + 3];
            float v0 = H[(size_t)s0 * 64 + lane];
            float v1 = H[(size_t)s1 * 64 + lane];
            float v2 = H[(size_t)s2 * 64 + lane];
            float v3 = H[(size_t)s3 * 64 + lane];
            acc += w0 * v0; acc += w1 * v1; acc += w2 * v2; acc += w3 * v3;
        }
        for (; j < end; j++) acc += nrm[j] * H[(size_t)col[j] * 64 + lane];
        out[(size_t)node * 64 + lane] = acc;
    } else {
        const float2* H2 = (const float2*)H;
        float2 acc; acc.x = 0.f; acc.y = 0.f;
        int j = beg;
        for (; j + 4 <= end; j += 4) {
            int   s0 = col[j + 0], s1 = col[j + 1], s2 = col[j + 2], s3 = col[j + 3];
            float w0 = nrm[j + 0], w1 = nrm[j + 1], w2 = nrm[j + 2], w3 = nrm[j + 3];
            float2 v0 = H2[(size_t)s0 * 64 + lane];
            float2 v1 = H2[(size_t)s1 * 64 + lane];
            float2 v2 = H2[(size_t)s2 * 64 + lane];
            float2 v3 = H2[(size_t)s3 * 64 + lane];
            acc.x += w0 * v0.x; acc.y += w0 * v0.y;
            acc.x += w1 * v1.x; acc.y += w1 * v1.y;
            acc.x += w2 * v2.x; acc.y += w2 * v2.y;
            acc.x += w3 * v3.x; acc.y += w3 * v3.y;
        }
        for (; j < end; j++) {
            float w = nrm[j];
            float2 v = H2[(size_t)col[j] * 64 + lane];
            acc.x += w * v.x; acc.y += w * v.y;
        }
        ((float2*)out)[(size_t)node * 64 + lane] = acc;
    }
}

// ---------------- Dense layer, F=128 outputs, conflict-free LDS, 4n x 16f per thread ----
// Block = 256 threads, 128 nodes/block. Thread t: fg=t&7 owns feats fg*4+32*j (j=0..3),
// mg=t>>3 owns local nodes mg*4+r (r=0..3). Ws ds_read_b128: 8 distinct addrs (fg) at
// banks 4fg..4fg+3 = all 32 banks, 8-lane broadcast each -> conflict-free. As (stride 33)
// ds_read_b32: banks 4*mg, broadcast -> conflict-free. Per k per wave: LDS ~72 cyc,
// VALU 128 cyc -> VALU-bound by design. acc = 64 VGPR; launch_bounds(256,3) caps ~170.
// DUAL: output cols 0..63 = Wa/ba -> Ca, 64..127 = Wb/bb -> Cb (fused mu/logvar heads).

template <int K, bool RELU, bool DUAL>
__global__ __launch_bounds__(256, 3) void gemm128_k(const float* __restrict__ A,
                                                    const float* __restrict__ Wa, const float* __restrict__ Wb,
                                                    const float* __restrict__ ba, const float* __restrict__ bb,
                                                    float* __restrict__ Ca, float* __restrict__ Cb, int n) {
    constexpr int F  = 128;
    constexpr int NT = 128;          // nodes per block
    constexpr int KC = 32;           // K chunk
    constexpr int AS = 33;           // As row stride (floats): 4*33 mod 32 = 4 -> 8 banks
    __shared__ __align__(16) float Ws[KC * F];   // 16 KB
    __shared__ float As[NT * AS];                // ~16.5 KB

    int t  = threadIdx.x;
    int fg = t & 7;
    int mg = t >> 3;
    int m0 = blockIdx.x * NT;

    float4 acc[4][4];                // [r][j]
#pragma unroll
    for (int r = 0; r < 4; r++)
#pragma unroll
        for (int j = 0; j < 4; j++) { acc[r][j].x = 0.f; acc[r][j].y = 0.f; acc[r][j].z = 0.f; acc[r][j].w = 0.f; }

    for (int kc = 0; kc < K; kc += KC) {
        // stage Ws chunk: KC*F/4 = 1024 float4, 4 per thread
        for (int e = t; e < KC * F / 4; e += 256) {
            float4 w;
            if (!DUAL) {
                w = ((const float4*)Wa)[(size_t)kc * (F / 4) + e];
            } else {
                int r = e >> 5;              // k row within chunk
                int c = (e & 31) * 4;        // float col 0..127
                w = (c < 64) ? *(const float4*)&Wa[(size_t)(kc + r) * 64 + c]
                             : *(const float4*)&Wb[(size_t)(kc + r) * 64 + (c - 64)];
            }
            ((float4*)Ws)[e] = w;
        }
        // stage As chunk: NT*KC floats, coalesced float4 reads, scalar LDS writes (pad 33)
        for (int e = t; e < NT * KC / 4; e += 256) {
            int r = e >> 3;                  // / (KC/4)
            int c = (e & 7) * 4;             // float col within chunk
            float4 v;
            if (m0 + r < n) v = *(const float4*)&A[(size_t)(m0 + r) * K + kc + c];
            else { v.x = 0.f; v.y = 0.f; v.z = 0.f; v.w = 0.f; }
            float* p = &As[r * AS + c];
            p[0] = v.x; p[1] = v.y; p[2] = v.z; p[3] = v.w;
        }
        __syncthreads();

#pragma unroll 4
        for (int k = 0; k < KC; k++) {
            float a0 = As[(mg * 4 + 0) * AS + k];
            float a1 = As[(mg * 4 + 1) * AS + k];
            float a2 = As[(mg * 4 + 2) * AS + k];
            float a3 = As[(mg * 4 + 3) * AS + k];
#pragma unroll
            for (int j = 0; j < 4; j++) {
                float4 w = *(const float4*)&Ws[k * F + fg * 4 + 32 * j];
                acc[0][j].x += a0 * w.x; acc[0][j].y += a0 * w.y; acc[0][j].z += a0 * w.z; acc[0][j].w += a0 * w.w;
                acc[1][j].x += a1 * w.x; acc[1][j].y += a1 * w.y; acc[1][j].z += a1 * w.z; acc[1][j].w += a1 * w.w;
                acc[2][j].x += a2 * w.x; acc[2][j].y += a2 * w.y; acc[2][j].z += a2 * w.z; acc[2][j].w += a2 * w.w;
                acc[3][j].x += a3 * w.x; acc[3][j].y += a3 * w.y; acc[3][j].z += a3 * w.z; acc[3][j].w += a3 * w.w;
            }
        }
        __syncthreads();
    }

    // epilogue: bias + optional relu; DUAL splits cols 0..63 / 64..127
#pragma unroll
    for (int r = 0; r < 4; r++) {
        int node = m0 + mg * 4 + r;
        if (node >= n) break;
#pragma unroll
        for (int j = 0; j < 4; j++) {
            int f = fg * 4 + 32 * j;
            float4 v = acc[r][j];
            const float* bp;
            float* cp;
            int fo;
            if (!DUAL) {
                bp = ba; cp = Ca + (size_t)node * F; fo = f;
            } else if (j < 2) {              // f < 64
                bp = ba; cp = Ca + (size_t)node * 64; fo = f;
            } else {
                bp = bb; cp = Cb + (size_t)node * 64; fo = f - 64;
            }
            v.x += bp[fo + 0]; v.y += bp[fo + 1]; v.z += bp[fo + 2]; v.w += bp[fo + 3];
            if (RELU) {
                v.x = fmaxf(v.x, 0.f); v.y = fmaxf(v.y, 0.f);
                v.z = fmaxf(v.z, 0.f); v.w = fmaxf(v.w, 0.f);
            }
            *(float4*)&cp[fo] = v;
        }
    }
}

// ---------------- launch ----------------

extern "C" void kernel_launch(void* const* d_in, const int* in_sizes, int n_in,
                              void* d_out, int out_size, void* d_ws, size_t ws_size,
                              hipStream_t stream) {
    const int N = N_NODES, E = N_EDGES, ETOT = E_TOT;

    const float* x    = (const float*)d_in[0];
    const int*   ei   = (const int*)d_in[1];
    const int*   srcA = ei;
    const int*   dstA = ei + E;
    const float* W1   = (const float*)d_in[2];
    const float* b1   = (const float*)d_in[3];
    const float* W2   = (const float*)d_in[4];
    const float* b2   = (const float*)d_in[5];
    const float* Wmu  = (const float*)d_in[6];
    const float* bmu  = (const float*)d_in[7];
    const float* Wlv  = (const float*)d_in[8];
    const float* blv  = (const float*)d_in[9];
    float* out = (float*)d_out;

    // workspace carve-out (~117 MB)
    char* ws = (char*)d_ws;
    size_t o = 0;
    auto alloc = [&](size_t bytes) -> void* {
        o = (o + 255) & ~(size_t)255;
        void* p = ws + o;
        o += bytes;
        return p;
    };
    int*   cnt    = (int*)alloc((size_t)N * 4);          // deg counts, later cursor
    int*   rowptr = (int*)alloc((size_t)(N + 1) * 4);
    float* dinv   = (float*)alloc((size_t)N * 4);
    int*   bsum   = (int*)alloc(512 * 4);
    int*   col    = (int*)alloc((size_t)ETOT * 4);
    float* nrm    = (float*)alloc((size_t)ETOT * 4);
    float* agg    = (float*)alloc((size_t)N * HIDDEN * 4);
    float* h      = (float*)alloc((size_t)N * HIDDEN * 4);
    (void)ws_size;

    const int gN = (N + 255) / 256;          // 391
    const int gE = (E + 255) / 256;          // 6250
    const int gT = (ETOT + 255) / 256;       // 6641
    const int gAgg = (N + 3) / 4;            // 25000 (4 nodes/block)
    const int gGemm = (N + 127) / 128;       // 782

    // CSR build
    init_cnt_k<<<gN, 256, 0, stream>>>(cnt, N);
    count_k<<<gE, 256, 0, stream>>>(dstA, cnt, E);
    dinv_k<<<gN, 256, 0, stream>>>(cnt, dinv, N);
    scan_block_k<<<gN, 256, 0, stream>>>(cnt, rowptr, bsum, N);
    scan_bsum_k<<<1, 512, 0, stream>>>(bsum, gN);
    scan_add_k<<<gN, 256, 0, stream>>>(rowptr, bsum, cnt /*cursor*/, N, ETOT);
    fill_k<<<gT, 256, 0, stream>>>(srcA, dstA, dinv, cnt, col, nrm, E, N);

    // layer 1: h = relu(Agg(x) @ W1 + b1)      (aggregate in 64-dim!)
    agg_k<64><<<gAgg, 256, 0, stream>>>(x, rowptr, col, nrm, agg, N);
    gemm128_k<64, true, false><<<gGemm, 256, 0, stream>>>(agg, W1, nullptr, b1, nullptr, h, nullptr, N);

    // layer 2: h = relu(Agg(h) @ W2 + b2)
    agg_k<128><<<gAgg, 256, 0, stream>>>(h, rowptr, col, nrm, agg, N);
    gemm128_k<128, true, false><<<gGemm, 256, 0, stream>>>(agg, W2, nullptr, b2, nullptr, h, nullptr, N);

    // heads: aggregate once, ONE fused GEMM (cols 0..63 = mu, 64..127 = logvar)
    agg_k<128><<<gAgg, 256, 0, stream>>>(h, rowptr, col, nrm, agg, N);
    gemm128_k<128, false, true><<<gGemm, 256, 0, stream>>>(agg, Wmu, Wlv, bmu, blv,
                                                           out, out + (size_t)N * Z_DIM, N);
}